// Round 11
// baseline (63.622 us; speedup 1.0000x reference)
//
#include <hip/hip_runtime.h>
#include <math.h>

// Problem constants (fixed by harness)
#define NN   128
#define TT   1024
#define SS   1024
#define H1D  512
#define H2D  128
#define OUTD 8

// NUFFT constants (R9-validated): grid Mr=2048, Gaussian width 12
#define MR    2048
#define WHALF 5
#define ALPHA 0.3702402f           // pi/sqrt(72)
#define BETA  6.35556e-6f          // pi^2/(ALPHA*MR^2)
#define DSCALE 0.3432943f          // sqrt(ALPHA/pi)

__device__ __forceinline__ float cos_rev(float r) { return __builtin_amdgcn_cosf(r); } // cos(2*pi*r)
__device__ __forceinline__ float sin_rev(float r) { return __builtin_amdgcn_sinf(r); } // sin(2*pi*r)

__device__ __forceinline__ float wave_sum(float v) {
#pragma unroll
    for (int off = 32; off > 0; off >>= 1) v += __shfl_xor(v, off, 64);
    return v;
}

// ---------------------------------------------------------------------------
// MEGAKERNEL: entire model per batch n. Block n, 1024 threads (16 waves).
//  a) twist + fast Gaussian gridding onto 2048-bin LDS grid (R9 verbatim math)
//  b) 2048-pt Stockham FFT in LDS (R9 verbatim), deconvolve -> freq[1024] LDS
//  c) layer-1: 16 waves x 32 rows; each row = 4 coalesced float4 wave-loads
//     (64 lanes x 4 chunks = 256 float4 = full K=1024)  [R10 bug: used 1 chunk]
//  d) layer-2: 2 chunks = K=512; e) layer-3 on wave 0 (K=128).
// ---------------------------------------------------------------------------
__global__ __launch_bounds__(1024) void k_mega(const float* __restrict__ inp,
                                               const float* __restrict__ W1,
                                               const float* __restrict__ b1,
                                               const float* __restrict__ W2,
                                               const float* __restrict__ b2,
                                               const float* __restrict__ W3,
                                               const float* __restrict__ b3,
                                               float* __restrict__ out) {
    const int n   = blockIdx.x;
    const int tid = threadIdx.x;          // 0..1023
    const int wid = tid >> 6, lane = tid & 63;

    __shared__ float2 Ag[MR];             // 16 KB (later: freq/h1/h2 overlay)
    __shared__ float2 Bg[MR];             // 16 KB (FFT ping-pong)

    // ---- zero grid ----
    Ag[tid] = make_float2(0.f, 0.f);
    Ag[tid + 1024] = make_float2(0.f, 0.f);

    // Gaussian table exp(-ALPHA*(k-5)^2)
    float T[12];
#pragma unroll
    for (int k = 0; k < 12; ++k) {
        const int kk = k - WHALF;
        T[k] = __expf(-ALPHA * (float)(kk * kk));
    }
    __syncthreads();

    // ---- a) twist + spread (1 point per thread) ----
    {
        const float* p = inp + (size_t)(n * TT + tid) * 3;
        const float x  = p[0];
        const float d  = p[2];
        const float df = d - floorf(d);            // exact for |d| < 2^23
        const float p512 = 512.0f * df;            // exact (pow2 scale)
        const float r512 = p512 - floorf(p512);
        const float cre = x * cos_rev(r512);
        const float cim = -x * sin_rev(r512);
        const float z  = df * 2048.0f;             // [0,2048)
        const int   j0 = (int)z;
        const float dl = z - (float)j0;
        float P = __expf(-ALPHA * dl * (dl + 10.0f));   // E1 * rho^-5
        const float R = __expf(2.0f * ALPHA * dl);      // rho
#pragma unroll
        for (int k = 0; k < 12; ++k) {
            const int gi = (j0 + k - WHALF) & (MR - 1);
            const float wk = P * T[k];
            atomicAdd(&Ag[gi].x, wk * cre);
            atomicAdd(&Ag[gi].y, wk * cim);
            P *= R;
        }
    }
    __syncthreads();

    // ---- b) Stockham radix-2 FFT, N=2048, 11 stages, 1 butterfly/thread ----
    float2* src = Ag;
    float2* dst = Bg;
#pragma unroll
    for (int s = 0; s < 11; ++s) {
        const int   m     = 1 << s;
        const float inv2l = 1.0f / (float)(2048 >> s);
        const int tau = tid;
        const int j   = tau >> s;
        const float r = (float)j * inv2l;
        const float cv = cos_rev(r), sv = sin_rev(r);  // w = cv - i*sv
        const float2 a = src[tau];
        const float2 b = src[tau + 1024];
        const int o = tau + (tau & ~(m - 1));
        dst[o] = make_float2(a.x + b.x, a.y + b.y);
        const float dr = a.x - b.x, di = a.y - b.y;
        dst[o + m] = make_float2(fmaf(di, sv, dr * cv),
                                 fmaf(di, cv, -dr * sv));
        __syncthreads();
        float2* tmp = src; src = dst; dst = tmp;
    }
    // after 11 swaps: data in Bg (src==Bg), Ag free for overlay

    float* freqL = (float*)Ag;            // [1024]
    float* h1L   = freqL + SS;            // [512]
    float* h2L   = h1L + H1D;             // [128]  (total 1664 floats < 4096)

    // ---- deconvolve + magnitude ----
    {
        const int ss = tid;
        const int sp = ss - 512;
        const int bin = (ss + 1536) & (MR - 1);
        const float2 v = src[bin];
        const float D = DSCALE * __expf(BETA * (float)(sp * sp));
        freqL[ss] = sqrtf(fmaf(v.x, v.x, v.y * v.y)) * D;
    }
    __syncthreads();

    // ---- c) layer 1: full K=1024 = 4 float4 chunks per lane ----
    {
        const float4* F4 = (const float4*)freqL;
        const float4 fq0 = F4[lane];
        const float4 fq1 = F4[64 + lane];
        const float4 fq2 = F4[128 + lane];
        const float4 fq3 = F4[192 + lane];
        const float4* W1v = (const float4*)W1;
#pragma unroll 2
        for (int jj = 0; jj < 32; ++jj) {
            const int j = wid * 32 + jj;
            const float4* Wr = W1v + (size_t)j * 256;
            const float4 w0 = Wr[lane];
            const float4 w1 = Wr[64 + lane];
            const float4 w2 = Wr[128 + lane];
            const float4 w3 = Wr[192 + lane];
            float a = fmaf(w0.x, fq0.x, fmaf(w0.y, fq0.y, fmaf(w0.z, fq0.z, w0.w * fq0.w)));
            a = fmaf(w1.x, fq1.x, fmaf(w1.y, fq1.y, fmaf(w1.z, fq1.z, fmaf(w1.w, fq1.w, a))));
            a = fmaf(w2.x, fq2.x, fmaf(w2.y, fq2.y, fmaf(w2.z, fq2.z, fmaf(w2.w, fq2.w, a))));
            a = fmaf(w3.x, fq3.x, fmaf(w3.y, fq3.y, fmaf(w3.z, fq3.z, fmaf(w3.w, fq3.w, a))));
            a = wave_sum(a);
            if (lane == 0) h1L[j] = 1.0f / (1.0f + __expf(-(a + b1[j])));
        }
    }
    __syncthreads();

    // ---- d) layer 2: K=512 = 2 float4 chunks per lane ----
    {
        const float4 h1a = ((const float4*)h1L)[lane];
        const float4 h1b = ((const float4*)h1L)[64 + lane];
        const float4* W2v = (const float4*)W2;
#pragma unroll 2
        for (int q = 0; q < 8; ++q) {
            const int j = wid * 8 + q;
            const float4 wa = W2v[(size_t)j * 128 + lane];
            const float4 wb = W2v[(size_t)j * 128 + 64 + lane];
            float a = fmaf(wa.x, h1a.x, fmaf(wa.y, h1a.y, fmaf(wa.z, h1a.z, wa.w * h1a.w)));
            a = fmaf(wb.x, h1b.x, fmaf(wb.y, h1b.y, fmaf(wb.z, h1b.z, fmaf(wb.w, h1b.w, a))));
            a = wave_sum(a);
            if (lane == 0) h2L[j] = 1.0f / (1.0f + __expf(-(a + b2[j])));
        }
    }
    __syncthreads();

    // ---- e) layer 3: wave 0 only (K=128 = float2 per lane) ----
    if (wid == 0) {
        const float2 h2 = ((const float2*)h2L)[lane];
        const float2* W3v = (const float2*)W3;
#pragma unroll
        for (int j = 0; j < OUTD; ++j) {
            const float2 w = W3v[j * 64 + lane];
            float a = fmaf(w.x, h2.x, w.y * h2.y);
            a = wave_sum(a);
            if (lane == 0) out[n * OUTD + j] = a + b3[j];
        }
    }
}

extern "C" void kernel_launch(void* const* d_in, const int* in_sizes, int n_in,
                              void* d_out, int out_size, void* d_ws, size_t ws_size,
                              hipStream_t stream) {
    (void)in_sizes; (void)n_in; (void)out_size; (void)d_ws; (void)ws_size;
    const float* inp = (const float*)d_in[0];
    const float* W1  = (const float*)d_in[1];
    const float* b1  = (const float*)d_in[2];
    const float* W2  = (const float*)d_in[3];
    const float* b2  = (const float*)d_in[4];
    const float* W3  = (const float*)d_in[5];
    const float* b3  = (const float*)d_in[6];
    float* out = (float*)d_out;

    k_mega<<<dim3(NN), dim3(1024), 0, stream>>>(inp, W1, b1, W2, b2, W3, b3, out);
}

// Round 12
// 51.752 us; speedup vs baseline: 1.2294x; 1.2294x over previous
//
#include <hip/hip_runtime.h>
#include <math.h>

// Problem constants (fixed by harness)
#define NN   128
#define TT   1024
#define SS   1024
#define H1D  512
#define H2D  128
#define OUTD 8
#define TCH  8      // t-chunks (TC=128 each, 2 halves of 64 per block)
#define TC   128
#define SPT  8      // s-values per thread (dual depth-3 rotation chains)
#define KQN  8      // layer-1 split-K chunks

// ws layout in floats (~11.3 MB)
#define OFF_RI   0                         // partials [ch][n][s] float2 (re,im)
#define OFF_FREQ (TCH*NN*SS*2)             // 2097152: freq [n][s]
#define OFF_P1   (OFF_FREQ + NN*SS)        // 2228224: P1 [8 kq][128 n][512 j]
#define OFF_H1   (OFF_P1 + KQN*NN*H1D)     // 2752512: h1 [n][512]
#define OFF_H2   (OFF_H1 + NN*H1D)         // 2818048: h2 [n][128] (end 2834432)

__device__ __forceinline__ float cos_rev(float r) { return __builtin_amdgcn_cosf(r); } // cos(2*pi*r)
__device__ __forceinline__ float sin_rev(float r) { return __builtin_amdgcn_sinf(r); } // sin(2*pi*r)

__device__ __forceinline__ float wave_sum(float v) {
#pragma unroll
    for (int off = 32; off > 0; off >>= 1) v += __shfl_xor(v, off, 64);
    return v;
}

// ---------------------------------------------------------------------------
// Kernel 1: partial NUDFT v2 (R8 verbatim, proven 54.6-config)
// ---------------------------------------------------------------------------
__global__ __launch_bounds__(256) void k_nudft(const float* __restrict__ inp,
                                               float* __restrict__ ws) {
    const int tc  = blockIdx.x;    // 0..7
    const int n   = blockIdx.y;    // 0..127
    const int tid = threadIdx.x;
    const int th  = tid >> 7;      // t-half 0/1
    const int sl  = tid & 127;     // s-lane

    __shared__ float4 shA[TC];     // {frac(day), x, cos(2pi d), sin(2pi d)}
    __shared__ float2 shB[TC];     // {cos(2pi 4d), sin(2pi 4d)}
    __shared__ float2 red[SPT][128];
    if (tid < TC) {
        const float* p = inp + (size_t)(n * TT + tc * TC + tid) * 3;
        const float x  = p[0];
        const float d  = p[2];
        const float df = d - floorf(d);            // exact for |d| < 2^23
        float r4 = 4.0f * df;
        r4 -= floorf(r4);
        shA[tid] = make_float4(df, x, cos_rev(df), sin_rev(df));
        shB[tid] = make_float2(cos_rev(r4), sin_rev(r4));
    }
    __syncthreads();

    const float s0f = (float)(sl * SPT);
    float2 acc[SPT];
#pragma unroll
    for (int q = 0; q < SPT; ++q) acc[q] = make_float2(0.f, 0.f);

#pragma unroll 2
    for (int i = 0; i < 64; ++i) {
        const int idx = th * 64 + i;
        const float4 v = shA[idx];                 // broadcast reads
        const float2 w = shB[idx];
        const float p   = s0f * v.x;
        const float plo = fmaf(s0f, v.x, -p);      // exact product residual
        const float r   = (p - floorf(p)) + plo;
        const float c  = cos_rev(r);
        const float sn = sin_rev(r);
        float cB = fmaf(-sn, w.y, c * w.x);
        float sB = fmaf( c,  w.y, sn * w.x);
        float cA = c, sA = sn;
        acc[0].x = fmaf(v.y, cA, acc[0].x); acc[0].y = fmaf(v.y, sA, acc[0].y);
        acc[4].x = fmaf(v.y, cB, acc[4].x); acc[4].y = fmaf(v.y, sB, acc[4].y);
#pragma unroll
        for (int q = 1; q < 4; ++q) {
            const float cA2 = fmaf(-sA, v.w, cA * v.z);
            const float sA2 = fmaf( cA, v.w, sA * v.z);
            const float cB2 = fmaf(-sB, v.w, cB * v.z);
            const float sB2 = fmaf( cB, v.w, sB * v.z);
            cA = cA2; sA = sA2; cB = cB2; sB = sB2;
            acc[q].x     = fmaf(v.y, cA, acc[q].x);
            acc[q].y     = fmaf(v.y, sA, acc[q].y);
            acc[q + 4].x = fmaf(v.y, cB, acc[q + 4].x);
            acc[q + 4].y = fmaf(v.y, sB, acc[q + 4].y);
        }
    }

    if (th == 1) {
#pragma unroll
        for (int q = 0; q < SPT; ++q) red[q][sl] = acc[q];
    }
    __syncthreads();
    if (th == 0) {
        float4* RI = (float4*)(ws + OFF_RI) +
                     ((((size_t)(tc * NN + n)) * SS + sl * SPT) >> 1);
#pragma unroll
        for (int q = 0; q < SPT / 2; ++q) {
            const float2 r0 = red[2*q][sl], r1 = red[2*q+1][sl];
            RI[q] = make_float4(acc[2*q].x + r0.x, acc[2*q].y + r0.y,
                                acc[2*q+1].x + r1.x, acc[2*q+1].y + r1.y);
        }
    }
}

// ---------------------------------------------------------------------------
// Kernel 2: combine t-chunk partials -> frequential (R8 verbatim)
// ---------------------------------------------------------------------------
__global__ __launch_bounds__(256) void k_combine1(float* __restrict__ ws) {
    const int idx = blockIdx.x * 256 + threadIdx.x;   // = n*SS + s
    const float2* P = (const float2*)(ws + OFF_RI);
    float re = 0.f, im = 0.f;
#pragma unroll
    for (int ch = 0; ch < TCH; ++ch) {
        const float2 v = P[(size_t)ch * (NN * SS) + idx];
        re += v.x; im += v.y;
    }
    ws[OFF_FREQ + idx] = sqrtf(fmaf(re, re, im * im));
}

// ---------------------------------------------------------------------------
// Kernel 3: layer-1 split-K partial GEMM (R8 verbatim, 8 k-chunks)
// ---------------------------------------------------------------------------
__global__ __launch_bounds__(256) void k_l1p(const float* __restrict__ W1,
                                             float* __restrict__ ws) {
    const int kq = blockIdx.x;   // 0..7   k-chunk of 128
    const int jq = blockIdx.y;   // 0..3   j-chunk of 128
    const int nb = blockIdx.z;   // 0..15  n-chunk of 8
    const int tid = threadIdx.x;

    __shared__ float4 Al[8][32];  // 8 n-rows x 128 k (as float4)
    const float4* FQ = (const float4*)(ws + OFF_FREQ);
    {
        const int row = tid >> 5, c4 = tid & 31;
        Al[row][c4] = FQ[(nb * 8 + row) * 256 + kq * 32 + c4];
    }
    __syncthreads();

    const int jl = tid & 127, ng = tid >> 7;
    const int j = jq * 128 + jl;
    const float4* W1v = (const float4*)W1;
    float a0 = 0.f, a1 = 0.f, a2 = 0.f, a3 = 0.f;
#pragma unroll 4
    for (int k4 = 0; k4 < 32; ++k4) {
        const float4 w  = W1v[(size_t)j * 256 + kq * 32 + k4];
        const float4 x0 = Al[ng * 4 + 0][k4];
        const float4 x1 = Al[ng * 4 + 1][k4];
        const float4 x2 = Al[ng * 4 + 2][k4];
        const float4 x3 = Al[ng * 4 + 3][k4];
        a0 = fmaf(x0.x, w.x, fmaf(x0.y, w.y, fmaf(x0.z, w.z, fmaf(x0.w, w.w, a0))));
        a1 = fmaf(x1.x, w.x, fmaf(x1.y, w.y, fmaf(x1.z, w.z, fmaf(x1.w, w.w, a1))));
        a2 = fmaf(x2.x, w.x, fmaf(x2.y, w.y, fmaf(x2.z, w.z, fmaf(x2.w, w.w, a2))));
        a3 = fmaf(x3.x, w.x, fmaf(x3.y, w.y, fmaf(x3.z, w.z, fmaf(x3.w, w.w, a3))));
    }
    float* P1 = ws + OFF_P1;
    const float acc[4] = {a0, a1, a2, a3};
#pragma unroll
    for (int i = 0; i < 4; ++i)
        P1[((size_t)(kq * NN + nb * 8 + ng * 4 + i)) * H1D + j] = acc[i];
}

// ---------------------------------------------------------------------------
// Kernel 4: combine layer-1 partials + bias + sigmoid -> h1 (R8 verbatim)
// ---------------------------------------------------------------------------
__global__ __launch_bounds__(256) void k_l1c(const float* __restrict__ b1,
                                             float* __restrict__ ws) {
    const int tid = blockIdx.x * 256 + threadIdx.x;   // = n*H1D + j
    const int j = tid & (H1D - 1);
    float s = b1[j];
#pragma unroll
    for (int kq = 0; kq < KQN; ++kq) s += ws[OFF_P1 + (size_t)kq * (NN * H1D) + tid];
    ws[OFF_H1 + tid] = 1.0f / (1.0f + __expf(-s));
}

// ---------------------------------------------------------------------------
// Kernel 5 (NEW, replaces half of k_l23): layer-2, one wave per (n,j).
// 16384 waves = 16/SIMD. Coalesced 1KB wave-loads of W2 row + h1 row,
// dot over K=512 (2 float4 chunks/lane), shfl-tree reduce, sigmoid -> h2.
// ---------------------------------------------------------------------------
__global__ __launch_bounds__(256) void k_l2(const float* __restrict__ W2,
                                            const float* __restrict__ b2,
                                            float* __restrict__ ws) {
    const int task = blockIdx.x * 4 + (threadIdx.x >> 6);   // 0..16383
    const int lane = threadIdx.x & 63;
    const int n = task >> 7, j = task & 127;

    const float4* W2v = (const float4*)W2 + (size_t)j * 128;
    const float4* H1v = (const float4*)(ws + OFF_H1) + (size_t)n * 128;
    const float4 wa = W2v[lane],      wb = W2v[64 + lane];
    const float4 ha = H1v[lane],      hb = H1v[64 + lane];
    float a = fmaf(wa.x, ha.x, fmaf(wa.y, ha.y, fmaf(wa.z, ha.z, wa.w * ha.w)));
    a = fmaf(wb.x, hb.x, fmaf(wb.y, hb.y, fmaf(wb.z, hb.z, fmaf(wb.w, hb.w, a))));
    a = wave_sum(a);
    if (lane == 0)
        ws[OFF_H2 + (size_t)n * H2D + j] = 1.0f / (1.0f + __expf(-(a + b2[j])));
}

// ---------------------------------------------------------------------------
// Kernel 6 (NEW): layer-3, one wave per (n,j). 1024 waves.
// ---------------------------------------------------------------------------
__global__ __launch_bounds__(256) void k_l3(const float* __restrict__ W3,
                                            const float* __restrict__ b3,
                                            const float* __restrict__ ws,
                                            float* __restrict__ out) {
    const int task = blockIdx.x * 4 + (threadIdx.x >> 6);   // 0..1023
    const int lane = threadIdx.x & 63;
    const int n = task >> 3, j = task & 7;

    const float2 w = ((const float2*)W3)[j * 64 + lane];
    const float2 h = ((const float2*)(ws + OFF_H2 + (size_t)n * H2D))[lane];
    float a = fmaf(w.x, h.x, w.y * h.y);
    a = wave_sum(a);
    if (lane == 0) out[n * OUTD + j] = a + b3[j];
}

extern "C" void kernel_launch(void* const* d_in, const int* in_sizes, int n_in,
                              void* d_out, int out_size, void* d_ws, size_t ws_size,
                              hipStream_t stream) {
    (void)in_sizes; (void)n_in; (void)out_size; (void)ws_size;
    const float* inp = (const float*)d_in[0];
    const float* W1  = (const float*)d_in[1];
    const float* b1  = (const float*)d_in[2];
    const float* W2  = (const float*)d_in[3];
    const float* b2  = (const float*)d_in[4];
    const float* W3  = (const float*)d_in[5];
    const float* b3  = (const float*)d_in[6];
    float* out = (float*)d_out;
    float* ws  = (float*)d_ws;

    k_nudft   <<<dim3(TCH, NN), dim3(256), 0, stream>>>(inp, ws);
    k_combine1<<<dim3(512),     dim3(256), 0, stream>>>(ws);
    k_l1p     <<<dim3(8, 4, 16),dim3(256), 0, stream>>>(W1, ws);
    k_l1c     <<<dim3(256),     dim3(256), 0, stream>>>(b1, ws);
    k_l2      <<<dim3(4096),    dim3(256), 0, stream>>>(W2, b2, ws);
    k_l3      <<<dim3(256),     dim3(256), 0, stream>>>(W3, b3, ws, out);
}